// Round 5
// baseline (1624.938 us; speedup 1.0000x reference)
//
#include <hip/hip_runtime.h>

// GraphSAGE on MI355X.
// adj is 0.001-dense (avg degree ~16). Build CSR in one 1.07 GB scan of adj
// (the roofline), then sparse mean-aggregation + fp32 dense GEMM per layer.
// R1: LDS-aggregated pair emission (1 global atomic/block, not per-edge).
// R2: pre-transposed weights Wt[256][FOUT] -> coalesced W streams in GEMM.
// R4: 4-way MLP in k_count; k_layer 8 nodes/block (2048 blocks = 32 waves/CU),
//     32 threads/node gather, edge loop unrolled x4 with batched index loads.

#define NN 16384          // nodes
#define FIN 128           // feature dim (all layer inputs)
#define CAP (1 << 19)     // edge capacity (expected ~268K)
#define LBUF 1024         // per-block LDS pair buffer (expected ~131 hits/block)

typedef int iv4 __attribute__((ext_vector_type(4)));   // native vector for ntload

// ---- workspace layout (bytes) ----
#define OFF_CNT   0u
#define OFF_DEG   256u
#define OFF_OFFS  65792u                               // 256 + 65536
#define OFF_CUR   131584u
#define OFF_DINV  197120u
#define OFF_PAIRS 262656u
#define OFF_ESRC  (262656u + 8u * CAP)                 // 4456960
#define OFF_WT0   (OFF_ESRC + 4u * CAP)                // 6554112
#define OFF_WT1   (OFF_WT0 + 131072u)                  // Wt0 [256][128] f32
#define OFF_WT2   (OFF_WT1 + 131072u)                  // Wt1 [256][128] f32
#define OFF_H1    (OFF_WT2 + 65536u)                   // Wt2 [256][64] f32
#define OFF_H2    (OFF_H1 + 4u * NN * FIN)

// ---------- kernel 0: transpose [Wl;Wr] -> Wt[256][FOUT] ----------
__global__ void k_wt(const float* __restrict__ Wl0, const float* __restrict__ Wr0,
                     const float* __restrict__ Wl1, const float* __restrict__ Wr1,
                     const float* __restrict__ Wl2, const float* __restrict__ Wr2,
                     float* __restrict__ wt0, float* __restrict__ wt1,
                     float* __restrict__ wt2) {
    int g = blockIdx.x * 256 + threadIdx.x;
    if (g < 32768) {
        int k = g >> 7, o = g & 127;
        wt0[g] = (k < 128) ? Wl0[o * 128 + k] : Wr0[o * 128 + (k - 128)];
    } else if (g < 65536) {
        int gg = g - 32768;
        int k = gg >> 7, o = gg & 127;
        wt1[gg] = (k < 128) ? Wl1[o * 128 + k] : Wr1[o * 128 + (k - 128)];
    } else if (g < 81920) {
        int gg = g - 65536;
        int k = gg >> 6, o = gg & 63;
        wt2[gg] = (k < 128) ? Wl2[o * 128 + k] : Wr2[o * 128 + (k - 128)];
    }
}

// ---------- kernel 1: scan adj once, count degrees, emit (s,t) pairs ----------
__device__ __forceinline__ void emit_hits(iv4 v, int idx4, int* __restrict__ deg,
                                          unsigned int* lcnt,
                                          unsigned long long* lbuf) {
    if ((v.x | v.y | v.z | v.w) == 0) return;   // fp 0.0f is all-zero bits
    int base = idx4 << 2;
    int s = base >> 14;            // row (source)
    int t = base & (NN - 1);       // col (target)
    int w[4] = {v.x, v.y, v.z, v.w};
    #pragma unroll
    for (int k = 0; k < 4; ++k) {
        if (w[k] != 0) {
            atomicAdd(&deg[t + k], 1);
            unsigned int idx = atomicAdd(lcnt, 1u);   // LDS atomic
            if (idx < LBUF)
                lbuf[idx] = ((unsigned long long)s << 32) | (unsigned)(t + k);
        }
    }
}

__global__ __launch_bounds__(256) void k_count(
    const iv4* __restrict__ adj4, int* __restrict__ deg,
    unsigned int* __restrict__ cnt, unsigned long long* __restrict__ pairs) {
    __shared__ unsigned int lcnt;
    __shared__ unsigned int lbase;
    __shared__ unsigned long long lbuf[LBUF];
    const int tid = threadIdx.x;
    if (tid == 0) lcnt = 0;
    __syncthreads();

    // total4 = 2^26, stride = 2^19, 32 iters x 4 independent in-flight loads
    const int stride = 2048 * 256;
    int i = blockIdx.x * 256 + tid;
    #pragma unroll 1
    for (int n = 0; n < 32; ++n, i += 4 * stride) {
        iv4 a = __builtin_nontemporal_load(&adj4[i]);
        iv4 b = __builtin_nontemporal_load(&adj4[i + stride]);
        iv4 c = __builtin_nontemporal_load(&adj4[i + 2 * stride]);
        iv4 d = __builtin_nontemporal_load(&adj4[i + 3 * stride]);
        emit_hits(a, i, deg, &lcnt, lbuf);
        emit_hits(b, i + stride, deg, &lcnt, lbuf);
        emit_hits(c, i + 2 * stride, deg, &lcnt, lbuf);
        emit_hits(d, i + 3 * stride, deg, &lcnt, lbuf);
    }
    __syncthreads();
    unsigned int total = lcnt;
    if (total > LBUF) total = LBUF;
    if (tid == 0) lbase = atomicAdd(cnt, total);           // 1 global atomic/block
    __syncthreads();
    unsigned int bb = lbase;
    for (unsigned int j = tid; j < total; j += 256)
        if (bb + j < CAP) pairs[bb + j] = lbuf[j];
}

// ---------- kernel 2: exclusive scan deg -> offsets, cursors, deg_inv ----------
__global__ __launch_bounds__(1024) void k_scan(
    const int* __restrict__ deg, int* __restrict__ offs,
    int* __restrict__ cur, float* __restrict__ dinv) {
    __shared__ int ps[1024];
    int tid = threadIdx.x;
    int base = tid * 16;
    int local = 0;
    #pragma unroll
    for (int j = 0; j < 16; ++j) local += deg[base + j];
    ps[tid] = local;
    __syncthreads();
    for (int ofs = 1; ofs < 1024; ofs <<= 1) {
        int v = (tid >= ofs) ? ps[tid - ofs] : 0;
        __syncthreads();
        ps[tid] += v;
        __syncthreads();
    }
    int run = ps[tid] - local;   // exclusive prefix
    #pragma unroll
    for (int j = 0; j < 16; ++j) {
        int d = deg[base + j];
        offs[base + j] = run;
        cur[base + j] = run;
        dinv[base + j] = d > 0 ? 1.0f / (float)d : 0.0f;
        run += d;
    }
    if (tid == 1023) offs[NN] = run;
}

// ---------- kernel 3: bin pairs into CSR edge_src ----------
__global__ void k_bin(const unsigned long long* __restrict__ pairs,
                      const unsigned int* __restrict__ cnt,
                      int* __restrict__ cur, int* __restrict__ esrc) {
    unsigned int total = *cnt;
    if (total > CAP) total = CAP;
    unsigned int stride = gridDim.x * blockDim.x;
    for (unsigned int i = blockIdx.x * blockDim.x + threadIdx.x; i < total; i += stride) {
        unsigned long long p = pairs[i];
        int s = (int)(p >> 32);
        int t = (int)(p & 0xFFFFFFFFull);
        int pos = atomicAdd(&cur[t], 1);
        esrc[pos] = s;
    }
}

// ---------- kernel 4: fused SAGE layer (mean-agg + Wt GEMM + bias (+ReLU)) ----
// 8 nodes/block, 2048 blocks (8 blocks/CU = 32 waves/CU, 100% occupancy).
// Gather: 32 threads/node, 1 float4/thread/edge (full 512B row per 32 lanes,
// coalesced), edge loop unrolled x4 with batched index loads (chain 16 -> 4x2).
// LDS z[8][264] floats: float4 slots [0,32)=agg, [32,64)=self, 2 pad.
template <int FOUT, bool RELU>
__global__ __launch_bounds__(256) void k_layer(
    const float4* __restrict__ hin,    // [NN][32] float4
    float* __restrict__ hout,          // [NN][FOUT]
    const int* __restrict__ esrc, const int* __restrict__ offs,
    const float* __restrict__ dinv,
    const float4* __restrict__ Wt4,    // [256][FOUT/4]
    const float* __restrict__ bias)    // [FOUT]
{
    constexpr int S4 = 66;             // float4 stride per node row
    __shared__ float4 z[8 * S4];
    const int tid = threadIdx.x;
    const int nodeBase = blockIdx.x * 8;
    const int nl = tid >> 5;           // 0..7 node-local
    const int q = tid & 31;            // 0..31 float4 lane within row

    // stage self row: 1 float4/thread, coalesced
    z[nl * S4 + 32 + q] = hin[(nodeBase + nl) * 32 + q];

    // mean aggregation
    {
        const int node = nodeBase + nl;
        const int e0 = offs[node], e1 = offs[node + 1];
        float4 acc = make_float4(0.f, 0.f, 0.f, 0.f);
        int e = e0;
        for (; e + 4 <= e1; e += 4) {
            int s0 = esrc[e], s1 = esrc[e + 1], s2 = esrc[e + 2], s3 = esrc[e + 3];
            float4 v0 = hin[s0 * 32 + q];
            float4 v1 = hin[s1 * 32 + q];
            float4 v2 = hin[s2 * 32 + q];
            float4 v3 = hin[s3 * 32 + q];
            acc.x += v0.x + v1.x + v2.x + v3.x;
            acc.y += v0.y + v1.y + v2.y + v3.y;
            acc.z += v0.z + v1.z + v2.z + v3.z;
            acc.w += v0.w + v1.w + v2.w + v3.w;
        }
        for (; e < e1; ++e) {
            float4 v = hin[esrc[e] * 32 + q];
            acc.x += v.x; acc.y += v.y; acc.z += v.z; acc.w += v.w;
        }
        const float di = dinv[node];
        acc.x *= di; acc.y *= di; acc.z *= di; acc.w *= di;
        z[nl * S4 + q] = acc;
    }
    __syncthreads();

    // GEMM: out[8 x FOUT] = [agg|self][8 x 256] @ Wt + b
    if constexpr (FOUT == 128) {
        const int to = tid & 31;       // output float4 col
        const int tn = tid >> 5;       // node
        float4 acc = make_float4(0.f, 0.f, 0.f, 0.f);
        #pragma unroll 4
        for (int k4 = 0; k4 < 64; ++k4) {
            float4 w0 = Wt4[(4 * k4 + 0) * 32 + to];
            float4 w1 = Wt4[(4 * k4 + 1) * 32 + to];
            float4 w2 = Wt4[(4 * k4 + 2) * 32 + to];
            float4 w3 = Wt4[(4 * k4 + 3) * 32 + to];
            float4 a = z[tn * S4 + k4];
            acc.x += a.x * w0.x + a.y * w1.x + a.z * w2.x + a.w * w3.x;
            acc.y += a.x * w0.y + a.y * w1.y + a.z * w2.y + a.w * w3.y;
            acc.z += a.x * w0.z + a.y * w1.z + a.z * w2.z + a.w * w3.z;
            acc.w += a.x * w0.w + a.y * w1.w + a.z * w2.w + a.w * w3.w;
        }
        const float4 bb = ((const float4*)bias)[to];
        float4 o;
        o.x = acc.x + bb.x; o.y = acc.y + bb.y;
        o.z = acc.z + bb.z; o.w = acc.w + bb.w;
        if (RELU) {
            o.x = fmaxf(o.x, 0.f); o.y = fmaxf(o.y, 0.f);
            o.z = fmaxf(o.z, 0.f); o.w = fmaxf(o.w, 0.f);
        }
        ((float4*)hout)[(nodeBase + tn) * 32 + to] = o;
    } else {                           // FOUT == 64: float2 per thread
        const float2* Wt2 = (const float2*)Wt4;   // [256][32]
        const int to = tid & 31;       // output float2 col
        const int tn = tid >> 5;       // node
        float2 acc = make_float2(0.f, 0.f);
        #pragma unroll 4
        for (int k4 = 0; k4 < 64; ++k4) {
            float2 w0 = Wt2[(4 * k4 + 0) * 32 + to];
            float2 w1 = Wt2[(4 * k4 + 1) * 32 + to];
            float2 w2 = Wt2[(4 * k4 + 2) * 32 + to];
            float2 w3 = Wt2[(4 * k4 + 3) * 32 + to];
            float4 a = z[tn * S4 + k4];
            acc.x += a.x * w0.x + a.y * w1.x + a.z * w2.x + a.w * w3.x;
            acc.y += a.x * w0.y + a.y * w1.y + a.z * w2.y + a.w * w3.y;
        }
        const float2 bb = ((const float2*)bias)[to];
        float2 o;
        o.x = acc.x + bb.x; o.y = acc.y + bb.y;
        if (RELU) { o.x = fmaxf(o.x, 0.f); o.y = fmaxf(o.y, 0.f); }
        ((float2*)hout)[(nodeBase + tn) * 32 + to] = o;
    }
}

extern "C" void kernel_launch(void* const* d_in, const int* in_sizes, int n_in,
                              void* d_out, int out_size, void* d_ws, size_t ws_size,
                              hipStream_t stream) {
    const float* x = (const float*)d_in[0];
    const iv4* adj4 = (const iv4*)d_in[1];
    const float* Wl0 = (const float*)d_in[2];
    const float* b0 = (const float*)d_in[3];
    const float* Wr0 = (const float*)d_in[4];
    const float* Wl1 = (const float*)d_in[5];
    const float* b1 = (const float*)d_in[6];
    const float* Wr1 = (const float*)d_in[7];
    const float* Wl2 = (const float*)d_in[8];
    const float* b2 = (const float*)d_in[9];
    const float* Wr2 = (const float*)d_in[10];

    char* ws = (char*)d_ws;
    unsigned int* cnt = (unsigned int*)(ws + OFF_CNT);
    int* deg = (int*)(ws + OFF_DEG);
    int* offs = (int*)(ws + OFF_OFFS);
    int* cur = (int*)(ws + OFF_CUR);
    float* dinv = (float*)(ws + OFF_DINV);
    unsigned long long* pairs = (unsigned long long*)(ws + OFF_PAIRS);
    int* esrc = (int*)(ws + OFF_ESRC);
    float* wt0 = (float*)(ws + OFF_WT0);
    float* wt1 = (float*)(ws + OFF_WT1);
    float* wt2 = (float*)(ws + OFF_WT2);
    float* h1 = (float*)(ws + OFF_H1);
    float* h2 = (float*)(ws + OFF_H2);

    // zero counter + deg (ws is poisoned 0xAA before every call)
    (void)hipMemsetAsync(ws, 0, OFF_OFFS, stream);

    // 0) transpose weights (tiny)
    k_wt<<<320, 256, 0, stream>>>(Wl0, Wr0, Wl1, Wr1, Wl2, Wr2, wt0, wt1, wt2);
    // 1) scan adj (the 1.07 GB roofline read)
    k_count<<<2048, 256, 0, stream>>>(adj4, deg, cnt, pairs);
    // 2) CSR offsets / cursors / deg_inv
    k_scan<<<1, 1024, 0, stream>>>(deg, offs, cur, dinv);
    // 3) bin edges
    k_bin<<<512, 256, 0, stream>>>(pairs, cnt, cur, esrc);
    // 4) three fused SAGE layers
    k_layer<128, true><<<NN / 8, 256, 0, stream>>>(
        (const float4*)x, h1, esrc, offs, dinv, (const float4*)wt0, b0);
    k_layer<128, true><<<NN / 8, 256, 0, stream>>>(
        (const float4*)h1, h2, esrc, offs, dinv, (const float4*)wt1, b1);
    k_layer<64, false><<<NN / 8, 256, 0, stream>>>(
        (const float4*)h2, (float*)d_out, esrc, offs, dinv, (const float4*)wt2, b2);
}

// Round 6
// 1454.000 us; speedup vs baseline: 1.1176x; 1.1176x over previous
//
#include <hip/hip_runtime.h>

// GraphSAGE on MI355X.
// adj is 0.001-dense (avg degree ~16). Build CSR in one 1.07 GB scan of adj
// (the roofline), then sparse mean-aggregation + fp32 dense GEMM per layer.
// R1: LDS-aggregated pair emission (1 global atomic/block, not per-edge).
// R2: pre-transposed weights Wt[256][FOUT] -> coalesced W streams in GEMM.
// R5 post-mortem: GEMM is L2-BW-bound on the per-wave Wt stream (Wt=128KB
//   > L1). 8 nodes/block doubled W traffic/out -> regression.
// R6: k_count reverted to R4 2-way (known good). k_layer 32 nodes/block,
//   NPT=4 (W bytes/out 4x better than R5, 2x better than R4); gather 8
//   thr/node x 4 float4, edge loop unrolled x2.

#define NN 16384          // nodes
#define FIN 128           // feature dim (all layer inputs)
#define CAP (1 << 19)     // edge capacity (expected ~268K)
#define LBUF 1024         // per-block LDS pair buffer (expected ~131 hits/block)

typedef int iv4 __attribute__((ext_vector_type(4)));   // native vector for ntload

// ---- workspace layout (bytes) ----
#define OFF_CNT   0u
#define OFF_DEG   256u
#define OFF_OFFS  65792u                               // 256 + 65536
#define OFF_CUR   131584u
#define OFF_DINV  197120u
#define OFF_PAIRS 262656u
#define OFF_ESRC  (262656u + 8u * CAP)                 // 4456960
#define OFF_WT0   (OFF_ESRC + 4u * CAP)                // 6554112
#define OFF_WT1   (OFF_WT0 + 131072u)                  // Wt0 [256][128] f32
#define OFF_WT2   (OFF_WT1 + 131072u)                  // Wt1 [256][128] f32
#define OFF_H1    (OFF_WT2 + 65536u)                   // Wt2 [256][64] f32
#define OFF_H2    (OFF_H1 + 4u * NN * FIN)

// ---------- kernel 0: transpose [Wl;Wr] -> Wt[256][FOUT] ----------
__global__ void k_wt(const float* __restrict__ Wl0, const float* __restrict__ Wr0,
                     const float* __restrict__ Wl1, const float* __restrict__ Wr1,
                     const float* __restrict__ Wl2, const float* __restrict__ Wr2,
                     float* __restrict__ wt0, float* __restrict__ wt1,
                     float* __restrict__ wt2) {
    int g = blockIdx.x * 256 + threadIdx.x;
    if (g < 32768) {
        int k = g >> 7, o = g & 127;
        wt0[g] = (k < 128) ? Wl0[o * 128 + k] : Wr0[o * 128 + (k - 128)];
    } else if (g < 65536) {
        int gg = g - 32768;
        int k = gg >> 7, o = gg & 127;
        wt1[gg] = (k < 128) ? Wl1[o * 128 + k] : Wr1[o * 128 + (k - 128)];
    } else if (g < 81920) {
        int gg = g - 65536;
        int k = gg >> 6, o = gg & 63;
        wt2[gg] = (k < 128) ? Wl2[o * 128 + k] : Wr2[o * 128 + (k - 128)];
    }
}

// ---------- kernel 1: scan adj once, count degrees, emit (s,t) pairs ----------
__device__ __forceinline__ void emit_hits(iv4 v, int idx4, int* __restrict__ deg,
                                          unsigned int* lcnt,
                                          unsigned long long* lbuf) {
    if ((v.x | v.y | v.z | v.w) == 0) return;   // fp 0.0f is all-zero bits
    int base = idx4 << 2;
    int s = base >> 14;            // row (source)
    int t = base & (NN - 1);       // col (target)
    int w[4] = {v.x, v.y, v.z, v.w};
    #pragma unroll
    for (int k = 0; k < 4; ++k) {
        if (w[k] != 0) {
            atomicAdd(&deg[t + k], 1);
            unsigned int idx = atomicAdd(lcnt, 1u);   // LDS atomic
            if (idx < LBUF)
                lbuf[idx] = ((unsigned long long)s << 32) | (unsigned)(t + k);
        }
    }
}

__global__ __launch_bounds__(256) void k_count(
    const iv4* __restrict__ adj4, int* __restrict__ deg,
    unsigned int* __restrict__ cnt, unsigned long long* __restrict__ pairs) {
    __shared__ unsigned int lcnt;
    __shared__ unsigned int lbase;
    __shared__ unsigned long long lbuf[LBUF];
    const int tid = threadIdx.x;
    if (tid == 0) lcnt = 0;
    __syncthreads();

    // total4 = 2^26, stride = 2048*256 = 2^19, 64 iters of 2 independent loads
    const int stride = 2048 * 256;
    int i = blockIdx.x * 256 + tid;
    #pragma unroll 1
    for (int n = 0; n < 64; ++n, i += 2 * stride) {
        iv4 a = __builtin_nontemporal_load(&adj4[i]);
        iv4 b = __builtin_nontemporal_load(&adj4[i + stride]);
        emit_hits(a, i, deg, &lcnt, lbuf);
        emit_hits(b, i + stride, deg, &lcnt, lbuf);
    }
    __syncthreads();
    unsigned int total = lcnt;
    if (total > LBUF) total = LBUF;
    if (tid == 0) lbase = atomicAdd(cnt, total);           // 1 global atomic/block
    __syncthreads();
    unsigned int bb = lbase;
    for (unsigned int j = tid; j < total; j += 256)
        if (bb + j < CAP) pairs[bb + j] = lbuf[j];
}

// ---------- kernel 2: exclusive scan deg -> offsets, cursors, deg_inv ----------
__global__ __launch_bounds__(1024) void k_scan(
    const int* __restrict__ deg, int* __restrict__ offs,
    int* __restrict__ cur, float* __restrict__ dinv) {
    __shared__ int ps[1024];
    int tid = threadIdx.x;
    int base = tid * 16;
    int local = 0;
    #pragma unroll
    for (int j = 0; j < 16; ++j) local += deg[base + j];
    ps[tid] = local;
    __syncthreads();
    for (int ofs = 1; ofs < 1024; ofs <<= 1) {
        int v = (tid >= ofs) ? ps[tid - ofs] : 0;
        __syncthreads();
        ps[tid] += v;
        __syncthreads();
    }
    int run = ps[tid] - local;   // exclusive prefix
    #pragma unroll
    for (int j = 0; j < 16; ++j) {
        int d = deg[base + j];
        offs[base + j] = run;
        cur[base + j] = run;
        dinv[base + j] = d > 0 ? 1.0f / (float)d : 0.0f;
        run += d;
    }
    if (tid == 1023) offs[NN] = run;
}

// ---------- kernel 3: bin pairs into CSR edge_src ----------
__global__ void k_bin(const unsigned long long* __restrict__ pairs,
                      const unsigned int* __restrict__ cnt,
                      int* __restrict__ cur, int* __restrict__ esrc) {
    unsigned int total = *cnt;
    if (total > CAP) total = CAP;
    unsigned int stride = gridDim.x * blockDim.x;
    for (unsigned int i = blockIdx.x * blockDim.x + threadIdx.x; i < total; i += stride) {
        unsigned long long p = pairs[i];
        int s = (int)(p >> 32);
        int t = (int)(p & 0xFFFFFFFFull);
        int pos = atomicAdd(&cur[t], 1);
        esrc[pos] = s;
    }
}

// ---------- kernel 4: fused SAGE layer (mean-agg + Wt GEMM + bias (+ReLU)) ----
// 32 nodes/block, 512 blocks, 4 blocks/CU (33.8 KB LDS) = 16 waves/CU.
// Gather: 8 threads/node x 4 float4 (512B/row across 8 lanes x4 slots),
// edge loop unrolled x2 (8 loads in flight). GEMM: NPT=4 -> each wave's
// 128KB Wt stream serves 8 nodes (W is L2-resident; L1 can't hold 128KB).
// LDS z[32][264] floats: float4 slots [0,32)=agg, [32,64)=self, 2 pad.
template <int FOUT, bool RELU>
__global__ __launch_bounds__(256) void k_layer(
    const float4* __restrict__ hin,    // [NN][32] float4
    float* __restrict__ hout,          // [NN][FOUT]
    const int* __restrict__ esrc, const int* __restrict__ offs,
    const float* __restrict__ dinv,
    const float4* __restrict__ Wt4,    // [256][FOUT/4]
    const float* __restrict__ bias)    // [FOUT]
{
    constexpr int S4 = 66;             // float4 stride per node row
    __shared__ float4 z[32 * S4];
    const int tid = threadIdx.x;
    const int nodeBase = blockIdx.x * 32;

    // stage self rows: 1024 float4s, coalesced (32 consecutive tids = one row)
    #pragma unroll
    for (int r = 0; r < 4; ++r) {
        int g = tid + 256 * r;
        int n = g >> 5, j = g & 31;
        z[n * S4 + 32 + j] = hin[(nodeBase + n) * 32 + j];
    }

    // mean aggregation: 8-thread cluster per node, 4 float4s/thread, unroll x2
    {
        const int nl = tid >> 3;       // 0..31 node-local
        const int q = tid & 7;         // 0..7
        const int node = nodeBase + nl;
        const int e0 = offs[node], e1 = offs[node + 1];
        float4 acc[4];
        #pragma unroll
        for (int k = 0; k < 4; ++k) acc[k] = make_float4(0.f, 0.f, 0.f, 0.f);
        int e = e0;
        for (; e + 2 <= e1; e += 2) {
            int s0 = esrc[e], s1 = esrc[e + 1];
            const float4* r0 = hin + s0 * 32;
            const float4* r1 = hin + s1 * 32;
            #pragma unroll
            for (int k = 0; k < 4; ++k) {
                float4 va = r0[q + 8 * k];
                float4 vb = r1[q + 8 * k];
                acc[k].x += va.x + vb.x; acc[k].y += va.y + vb.y;
                acc[k].z += va.z + vb.z; acc[k].w += va.w + vb.w;
            }
        }
        if (e < e1) {
            const float4* r0 = hin + esrc[e] * 32;
            #pragma unroll
            for (int k = 0; k < 4; ++k) {
                float4 va = r0[q + 8 * k];
                acc[k].x += va.x; acc[k].y += va.y;
                acc[k].z += va.z; acc[k].w += va.w;
            }
        }
        const float di = dinv[node];
        #pragma unroll
        for (int k = 0; k < 4; ++k) {
            acc[k].x *= di; acc[k].y *= di; acc[k].z *= di; acc[k].w *= di;
            z[nl * S4 + q + 8 * k] = acc[k];
        }
    }
    __syncthreads();

    // GEMM: out[32 x FOUT] = [agg|self][32 x 256] @ Wt + b
    constexpr int TO = FOUT / 4;       // 32 or 16
    constexpr int TN = 256 / TO;       // 8 or 16
    constexpr int NPT = 32 / TN;       // 4 or 2
    const int to = tid % TO;
    const int tn = tid / TO;

    float4 acc[NPT];
    #pragma unroll
    for (int m = 0; m < NPT; ++m) acc[m] = make_float4(0.f, 0.f, 0.f, 0.f);

    #pragma unroll 2
    for (int k4 = 0; k4 < 64; ++k4) {
        // Wt rows 4k4..4k4+3 at float4-col `to`: contiguous across lanes
        float4 w0 = Wt4[(4 * k4 + 0) * TO + to];
        float4 w1 = Wt4[(4 * k4 + 1) * TO + to];
        float4 w2 = Wt4[(4 * k4 + 2) * TO + to];
        float4 w3 = Wt4[(4 * k4 + 3) * TO + to];
        #pragma unroll
        for (int m = 0; m < NPT; ++m) {
            float4 a = z[(tn * NPT + m) * S4 + k4];   // ks 4k4..4k4+3
            acc[m].x += a.x * w0.x + a.y * w1.x + a.z * w2.x + a.w * w3.x;
            acc[m].y += a.x * w0.y + a.y * w1.y + a.z * w2.y + a.w * w3.y;
            acc[m].z += a.x * w0.z + a.y * w1.z + a.z * w2.z + a.w * w3.z;
            acc[m].w += a.x * w0.w + a.y * w1.w + a.z * w2.w + a.w * w3.w;
        }
    }

    // epilogue: +bias, optional ReLU, coalesced float4 store
    const float4 bb = ((const float4*)bias)[to];
    #pragma unroll
    for (int m = 0; m < NPT; ++m) {
        float4 o;
        o.x = acc[m].x + bb.x; o.y = acc[m].y + bb.y;
        o.z = acc[m].z + bb.z; o.w = acc[m].w + bb.w;
        if (RELU) {
            o.x = fmaxf(o.x, 0.f); o.y = fmaxf(o.y, 0.f);
            o.z = fmaxf(o.z, 0.f); o.w = fmaxf(o.w, 0.f);
        }
        ((float4*)hout)[(nodeBase + tn * NPT + m) * TO + to] = o;
    }
}

extern "C" void kernel_launch(void* const* d_in, const int* in_sizes, int n_in,
                              void* d_out, int out_size, void* d_ws, size_t ws_size,
                              hipStream_t stream) {
    const float* x = (const float*)d_in[0];
    const iv4* adj4 = (const iv4*)d_in[1];
    const float* Wl0 = (const float*)d_in[2];
    const float* b0 = (const float*)d_in[3];
    const float* Wr0 = (const float*)d_in[4];
    const float* Wl1 = (const float*)d_in[5];
    const float* b1 = (const float*)d_in[6];
    const float* Wr1 = (const float*)d_in[7];
    const float* Wl2 = (const float*)d_in[8];
    const float* b2 = (const float*)d_in[9];
    const float* Wr2 = (const float*)d_in[10];

    char* ws = (char*)d_ws;
    unsigned int* cnt = (unsigned int*)(ws + OFF_CNT);
    int* deg = (int*)(ws + OFF_DEG);
    int* offs = (int*)(ws + OFF_OFFS);
    int* cur = (int*)(ws + OFF_CUR);
    float* dinv = (float*)(ws + OFF_DINV);
    unsigned long long* pairs = (unsigned long long*)(ws + OFF_PAIRS);
    int* esrc = (int*)(ws + OFF_ESRC);
    float* wt0 = (float*)(ws + OFF_WT0);
    float* wt1 = (float*)(ws + OFF_WT1);
    float* wt2 = (float*)(ws + OFF_WT2);
    float* h1 = (float*)(ws + OFF_H1);
    float* h2 = (float*)(ws + OFF_H2);

    // zero counter + deg (ws is poisoned 0xAA before every call)
    (void)hipMemsetAsync(ws, 0, OFF_OFFS, stream);

    // 0) transpose weights (tiny)
    k_wt<<<320, 256, 0, stream>>>(Wl0, Wr0, Wl1, Wr1, Wl2, Wr2, wt0, wt1, wt2);
    // 1) scan adj (the 1.07 GB roofline read)
    k_count<<<2048, 256, 0, stream>>>(adj4, deg, cnt, pairs);
    // 2) CSR offsets / cursors / deg_inv
    k_scan<<<1, 1024, 0, stream>>>(deg, offs, cur, dinv);
    // 3) bin edges
    k_bin<<<512, 256, 0, stream>>>(pairs, cnt, cur, esrc);
    // 4) three fused SAGE layers
    k_layer<128, true><<<NN / 32, 256, 0, stream>>>(
        (const float4*)x, h1, esrc, offs, dinv, (const float4*)wt0, b0);
    k_layer<128, true><<<NN / 32, 256, 0, stream>>>(
        (const float4*)h1, h2, esrc, offs, dinv, (const float4*)wt1, b1);
    k_layer<64, false><<<NN / 32, 256, 0, stream>>>(
        (const float4*)h2, (float*)d_out, esrc, offs, dinv, (const float4*)wt2, b2);
}

// Round 7
// 1435.818 us; speedup vs baseline: 1.1317x; 1.0127x over previous
//
#include <hip/hip_runtime.h>

// GraphSAGE on MI355X.
// adj is 0.001-dense (avg degree ~16). One 1.07 GB scan of adj (the roofline)
// scatters edges DIRECTLY into per-target slot lists (atomicAdd on deg returns
// the slot index) -> no pairs buffer, no scan, no bin. Then 3 fused layers:
// sparse mean-aggregation + fp32 dense GEMM (no fp32 MFMA on CDNA4).
// R1: LDS-aggregated emission. R2: pre-transposed Wt (coalesced W streams).
// R6: 32 nodes/block, NPT=4 (W L2-traffic/out optimal: wave's 128KB Wt stream
//     serves 8 nodes). R7: direct-slot scatter kills k_scan/k_bin/pairs/memset
//     (deg zeroing folded into k_wt, which precedes k_count on the stream).

#define NN 16384          // nodes
#define SLOTC 64          // per-target slot capacity (deg~Pois(16.4); P(>64)~1e-19)

typedef int iv4 __attribute__((ext_vector_type(4)));   // native vector for ntload

// ---- workspace layout (bytes) ----
#define OFF_DEG   0u
#define OFF_SLOT  65536u                               // int[16384*64] = 4 MB
#define OFF_WT0   (65536u + 4194304u)                  // 4259840
#define OFF_WT1   (OFF_WT0 + 131072u)                  // Wt0 [256][128] f32
#define OFF_WT2   (OFF_WT1 + 131072u)                  // Wt1 [256][128] f32
#define OFF_H1    (OFF_WT2 + 65536u)                   // Wt2 [256][64] f32
#define OFF_H2    (OFF_H1 + 4u * NN * 128u)

// ---------- kernel 0: transpose [Wl;Wr] -> Wt[256][FOUT]; zero deg ----------
__global__ void k_wt(const float* __restrict__ Wl0, const float* __restrict__ Wr0,
                     const float* __restrict__ Wl1, const float* __restrict__ Wr1,
                     const float* __restrict__ Wl2, const float* __restrict__ Wr2,
                     float* __restrict__ wt0, float* __restrict__ wt1,
                     float* __restrict__ wt2, int* __restrict__ deg) {
    int g = blockIdx.x * 256 + threadIdx.x;
    if (g < NN) deg[g] = 0;            // runs before k_count on the stream
    if (g < 32768) {
        int k = g >> 7, o = g & 127;
        wt0[g] = (k < 128) ? Wl0[o * 128 + k] : Wr0[o * 128 + (k - 128)];
    } else if (g < 65536) {
        int gg = g - 32768;
        int k = gg >> 7, o = gg & 127;
        wt1[gg] = (k < 128) ? Wl1[o * 128 + k] : Wr1[o * 128 + (k - 128)];
    } else if (g < 81920) {
        int gg = g - 65536;
        int k = gg >> 6, o = gg & 63;
        wt2[gg] = (k < 128) ? Wl2[o * 128 + k] : Wr2[o * 128 + (k - 128)];
    }
}

// ---------- kernel 1: scan adj once, scatter edges into slot lists ----------
__device__ __forceinline__ void emit_hits(iv4 v, int idx4, int* __restrict__ deg,
                                          int* __restrict__ slots) {
    if ((v.x | v.y | v.z | v.w) == 0) return;   // fp 0.0f is all-zero bits
    int base = idx4 << 2;
    int s = base >> 14;            // row (source)
    int t = base & (NN - 1);       // col (target)
    int w[4] = {v.x, v.y, v.z, v.w};
    #pragma unroll
    for (int k = 0; k < 4; ++k) {
        if (w[k] != 0) {
            int pos = atomicAdd(&deg[t + k], 1);   // returns slot index
            if (pos < SLOTC) slots[(t + k) * SLOTC + pos] = s;
        }
    }
}

__global__ __launch_bounds__(256) void k_count(
    const iv4* __restrict__ adj4, int* __restrict__ deg,
    int* __restrict__ slots) {
    // total4 = 2^26, stride = 2048*256 = 2^19, 64 iters of 2 independent loads
    const int stride = 2048 * 256;
    int i = blockIdx.x * 256 + threadIdx.x;
    #pragma unroll 1
    for (int n = 0; n < 64; ++n, i += 2 * stride) {
        iv4 a = __builtin_nontemporal_load(&adj4[i]);
        iv4 b = __builtin_nontemporal_load(&adj4[i + stride]);
        emit_hits(a, i, deg, slots);
        emit_hits(b, i + stride, deg, slots);
    }
}

// ---------- kernel 2: fused SAGE layer (mean-agg + Wt GEMM + bias (+ReLU)) ----
// 32 nodes/block, 512 blocks (2/CU). Gather: 8 threads/node x 4 float4,
// edge loop unrolled x2 (8 row loads in flight); edge list = slots[node*64..].
// GEMM: NPT=4 -> each wave's 128KB Wt stream serves 8 nodes (W is L2-resident).
// LDS z[32][264] floats: float4 slots [0,32)=agg, [32,64)=self, 2 pad.
template <int FOUT, bool RELU>
__global__ __launch_bounds__(256) void k_layer(
    const float4* __restrict__ hin,    // [NN][32] float4
    float* __restrict__ hout,          // [NN][FOUT]
    const int* __restrict__ slots, const int* __restrict__ deg,
    const float4* __restrict__ Wt4,    // [256][FOUT/4]
    const float* __restrict__ bias)    // [FOUT]
{
    constexpr int S4 = 66;             // float4 stride per node row
    __shared__ float4 z[32 * S4];
    const int tid = threadIdx.x;
    const int nodeBase = blockIdx.x * 32;

    // stage self rows: 1024 float4s, coalesced (32 consecutive tids = one row)
    #pragma unroll
    for (int r = 0; r < 4; ++r) {
        int g = tid + 256 * r;
        int n = g >> 5, j = g & 31;
        z[n * S4 + 32 + j] = hin[(nodeBase + n) * 32 + j];
    }

    // mean aggregation: 8-thread cluster per node, 4 float4s/thread, unroll x2
    {
        const int nl = tid >> 3;       // 0..31 node-local
        const int q = tid & 7;         // 0..7
        const int node = nodeBase + nl;
        const int d = deg[node];
        const int dc = d < SLOTC ? d : SLOTC;
        const int* el = slots + node * SLOTC;
        float4 acc[4];
        #pragma unroll
        for (int k = 0; k < 4; ++k) acc[k] = make_float4(0.f, 0.f, 0.f, 0.f);
        int e = 0;
        for (; e + 2 <= dc; e += 2) {
            int s0 = el[e], s1 = el[e + 1];
            const float4* r0 = hin + s0 * 32;
            const float4* r1 = hin + s1 * 32;
            #pragma unroll
            for (int k = 0; k < 4; ++k) {
                float4 va = r0[q + 8 * k];
                float4 vb = r1[q + 8 * k];
                acc[k].x += va.x + vb.x; acc[k].y += va.y + vb.y;
                acc[k].z += va.z + vb.z; acc[k].w += va.w + vb.w;
            }
        }
        if (e < dc) {
            const float4* r0 = hin + el[e] * 32;
            #pragma unroll
            for (int k = 0; k < 4; ++k) {
                float4 va = r0[q + 8 * k];
                acc[k].x += va.x; acc[k].y += va.y;
                acc[k].z += va.z; acc[k].w += va.w;
            }
        }
        const float di = d > 0 ? 1.0f / (float)d : 0.0f;
        #pragma unroll
        for (int k = 0; k < 4; ++k) {
            acc[k].x *= di; acc[k].y *= di; acc[k].z *= di; acc[k].w *= di;
            z[nl * S4 + q + 8 * k] = acc[k];
        }
    }
    __syncthreads();

    // GEMM: out[32 x FOUT] = [agg|self][32 x 256] @ Wt + b
    constexpr int TO = FOUT / 4;       // 32 or 16
    constexpr int TN = 256 / TO;       // 8 or 16
    constexpr int NPT = 32 / TN;       // 4 or 2
    const int to = tid % TO;
    const int tn = tid / TO;

    float4 acc[NPT];
    #pragma unroll
    for (int m = 0; m < NPT; ++m) acc[m] = make_float4(0.f, 0.f, 0.f, 0.f);

    #pragma unroll 2
    for (int k4 = 0; k4 < 64; ++k4) {
        // Wt rows 4k4..4k4+3 at float4-col `to`: contiguous across lanes
        float4 w0 = Wt4[(4 * k4 + 0) * TO + to];
        float4 w1 = Wt4[(4 * k4 + 1) * TO + to];
        float4 w2 = Wt4[(4 * k4 + 2) * TO + to];
        float4 w3 = Wt4[(4 * k4 + 3) * TO + to];
        #pragma unroll
        for (int m = 0; m < NPT; ++m) {
            float4 a = z[(tn * NPT + m) * S4 + k4];   // ks 4k4..4k4+3
            acc[m].x += a.x * w0.x + a.y * w1.x + a.z * w2.x + a.w * w3.x;
            acc[m].y += a.x * w0.y + a.y * w1.y + a.z * w2.y + a.w * w3.y;
            acc[m].z += a.x * w0.z + a.y * w1.z + a.z * w2.z + a.w * w3.z;
            acc[m].w += a.x * w0.w + a.y * w1.w + a.z * w2.w + a.w * w3.w;
        }
    }

    // epilogue: +bias, optional ReLU, coalesced float4 store
    const float4 bb = ((const float4*)bias)[to];
    #pragma unroll
    for (int m = 0; m < NPT; ++m) {
        float4 o;
        o.x = acc[m].x + bb.x; o.y = acc[m].y + bb.y;
        o.z = acc[m].z + bb.z; o.w = acc[m].w + bb.w;
        if (RELU) {
            o.x = fmaxf(o.x, 0.f); o.y = fmaxf(o.y, 0.f);
            o.z = fmaxf(o.z, 0.f); o.w = fmaxf(o.w, 0.f);
        }
        ((float4*)hout)[(nodeBase + tn * NPT + m) * TO + to] = o;
    }
}

extern "C" void kernel_launch(void* const* d_in, const int* in_sizes, int n_in,
                              void* d_out, int out_size, void* d_ws, size_t ws_size,
                              hipStream_t stream) {
    const float* x = (const float*)d_in[0];
    const iv4* adj4 = (const iv4*)d_in[1];
    const float* Wl0 = (const float*)d_in[2];
    const float* b0 = (const float*)d_in[3];
    const float* Wr0 = (const float*)d_in[4];
    const float* Wl1 = (const float*)d_in[5];
    const float* b1 = (const float*)d_in[6];
    const float* Wr1 = (const float*)d_in[7];
    const float* Wl2 = (const float*)d_in[8];
    const float* b2 = (const float*)d_in[9];
    const float* Wr2 = (const float*)d_in[10];

    char* ws = (char*)d_ws;
    int* deg = (int*)(ws + OFF_DEG);
    int* slots = (int*)(ws + OFF_SLOT);
    float* wt0 = (float*)(ws + OFF_WT0);
    float* wt1 = (float*)(ws + OFF_WT1);
    float* wt2 = (float*)(ws + OFF_WT2);
    float* h1 = (float*)(ws + OFF_H1);
    float* h2 = (float*)(ws + OFF_H2);

    // 0) transpose weights + zero deg (precedes k_count on this stream)
    k_wt<<<320, 256, 0, stream>>>(Wl0, Wr0, Wl1, Wr1, Wl2, Wr2,
                                  wt0, wt1, wt2, deg);
    // 1) scan adj (the 1.07 GB roofline read), scatter edges into slots
    k_count<<<2048, 256, 0, stream>>>(adj4, deg, slots);
    // 2) three fused SAGE layers
    k_layer<128, true><<<NN / 32, 256, 0, stream>>>(
        (const float4*)x, h1, slots, deg, (const float4*)wt0, b0);
    k_layer<128, true><<<NN / 32, 256, 0, stream>>>(
        (const float4*)h1, h2, slots, deg, (const float4*)wt1, b1);
    k_layer<64, false><<<NN / 32, 256, 0, stream>>>(
        (const float4*)h2, (float*)d_out, slots, deg, (const float4*)wt2, b2);
}

// Round 8
// 1414.790 us; speedup vs baseline: 1.1485x; 1.0149x over previous
//
#include <hip/hip_runtime.h>

// GraphSAGE on MI355X.
// adj is 0.001-dense (avg degree ~16). One 1.07 GB scan of adj (the roofline)
// scatters edges DIRECTLY into per-target slot lists (atomicAdd on deg returns
// the slot index). Then 3 fused layers: sparse mean-agg + fp32 dense GEMM.
// R2: pre-transposed Wt (coalesced W streams). R6: 32 nodes/block, NPT=4
// (wave's 128KB Wt stream serves 8 nodes). R7: direct-slot scatter (no
// scan/bin/pairs/memset). R8: k_count explicitly software-pipelined (2-ahead
// prefetch, 4 loads in flight across the branchy emit); gather uses int4
// index loads + 4-row unroll (16 row loads in flight per cluster).

#define NN 16384          // nodes
#define SLOTC 64          // per-target slot capacity (deg~Pois(16.4); P(>64)~1e-19)

typedef int iv4 __attribute__((ext_vector_type(4)));   // native vector for ntload

// ---- workspace layout (bytes) ----
#define OFF_DEG   0u
#define OFF_SLOT  65536u                               // int[16384*64] = 4 MB
#define OFF_WT0   (65536u + 4194304u)                  // 4259840
#define OFF_WT1   (OFF_WT0 + 131072u)                  // Wt0 [256][128] f32
#define OFF_WT2   (OFF_WT1 + 131072u)                  // Wt1 [256][128] f32
#define OFF_H1    (OFF_WT2 + 65536u)                   // Wt2 [256][64] f32
#define OFF_H2    (OFF_H1 + 4u * NN * 128u)

// ---------- kernel 0: transpose [Wl;Wr] -> Wt[256][FOUT]; zero deg ----------
__global__ void k_wt(const float* __restrict__ Wl0, const float* __restrict__ Wr0,
                     const float* __restrict__ Wl1, const float* __restrict__ Wr1,
                     const float* __restrict__ Wl2, const float* __restrict__ Wr2,
                     float* __restrict__ wt0, float* __restrict__ wt1,
                     float* __restrict__ wt2, int* __restrict__ deg) {
    int g = blockIdx.x * 256 + threadIdx.x;
    if (g < NN) deg[g] = 0;            // runs before k_count on the stream
    if (g < 32768) {
        int k = g >> 7, o = g & 127;
        wt0[g] = (k < 128) ? Wl0[o * 128 + k] : Wr0[o * 128 + (k - 128)];
    } else if (g < 65536) {
        int gg = g - 32768;
        int k = gg >> 7, o = gg & 127;
        wt1[gg] = (k < 128) ? Wl1[o * 128 + k] : Wr1[o * 128 + (k - 128)];
    } else if (g < 81920) {
        int gg = g - 65536;
        int k = gg >> 6, o = gg & 63;
        wt2[gg] = (k < 128) ? Wl2[o * 128 + k] : Wr2[o * 128 + (k - 128)];
    }
}

// ---------- kernel 1: scan adj once, scatter edges into slot lists ----------
__device__ __forceinline__ void emit_hits(iv4 v, int idx4, int* __restrict__ deg,
                                          int* __restrict__ slots) {
    if ((v.x | v.y | v.z | v.w) == 0) return;   // fp 0.0f is all-zero bits
    int base = idx4 << 2;
    int s = base >> 14;            // row (source)
    int t = base & (NN - 1);       // col (target)
    int w[4] = {v.x, v.y, v.z, v.w};
    #pragma unroll
    for (int k = 0; k < 4; ++k) {
        if (w[k] != 0) {
            int pos = atomicAdd(&deg[t + k], 1);   // returns slot index
            if (pos < SLOTC) slots[(t + k) * SLOTC + pos] = s;
        }
    }
}

// Explicit software pipeline: loads for iter n+1 are issued BEFORE the branchy
// emit of iter n, so the wave waits vmcnt(2), not vmcnt(0) -> latency overlap.
__global__ __launch_bounds__(256) void k_count(
    const iv4* __restrict__ adj4, int* __restrict__ deg,
    int* __restrict__ slots) {
    const int stride = 2048 * 256;         // 2^19; total4 = 2^26 = 128 strides
    int i = blockIdx.x * 256 + threadIdx.x;
    iv4 a = __builtin_nontemporal_load(&adj4[i]);
    iv4 b = __builtin_nontemporal_load(&adj4[i + stride]);
    #pragma unroll 1
    for (int n = 0; n < 63; ++n) {
        iv4 c = __builtin_nontemporal_load(&adj4[i + 2 * stride]);
        iv4 d = __builtin_nontemporal_load(&adj4[i + 3 * stride]);
        emit_hits(a, i, deg, slots);
        emit_hits(b, i + stride, deg, slots);
        a = c; b = d; i += 2 * stride;
    }
    emit_hits(a, i, deg, slots);
    emit_hits(b, i + stride, deg, slots);
}

// ---------- kernel 2: fused SAGE layer (mean-agg + Wt GEMM + bias (+ReLU)) ----
// 32 nodes/block, 512 blocks. Gather: 8 threads/node x 4 float4; int4 index
// load gives 4 edges -> 16 independent row loads in flight per cluster.
// GEMM: NPT=4 -> wave's 128KB Wt stream serves 8 nodes (W is L2-resident).
// LDS z[32][264] floats: float4 slots [0,32)=agg, [32,64)=self, 2 pad.
template <int FOUT, bool RELU>
__global__ __launch_bounds__(256) void k_layer(
    const float4* __restrict__ hin,    // [NN][32] float4
    float* __restrict__ hout,          // [NN][FOUT]
    const int* __restrict__ slots, const int* __restrict__ deg,
    const float4* __restrict__ Wt4,    // [256][FOUT/4]
    const float* __restrict__ bias)    // [FOUT]
{
    constexpr int S4 = 66;             // float4 stride per node row
    __shared__ float4 z[32 * S4];
    const int tid = threadIdx.x;
    const int nodeBase = blockIdx.x * 32;

    // stage self rows: 1024 float4s, coalesced (32 consecutive tids = one row)
    #pragma unroll
    for (int r = 0; r < 4; ++r) {
        int g = tid + 256 * r;
        int n = g >> 5, j = g & 31;
        z[n * S4 + 32 + j] = hin[(nodeBase + n) * 32 + j];
    }

    // mean aggregation: 8-thread cluster per node, 4 float4s/thread,
    // int4 index loads + 4-row unroll
    {
        const int nl = tid >> 3;       // 0..31 node-local
        const int q = tid & 7;         // 0..7
        const int node = nodeBase + nl;
        const int d = deg[node];
        const int dc = d < SLOTC ? d : SLOTC;
        const int* el = slots + node * SLOTC;   // 256B-aligned
        float4 acc[4];
        #pragma unroll
        for (int k = 0; k < 4; ++k) acc[k] = make_float4(0.f, 0.f, 0.f, 0.f);
        int e = 0;
        for (; e + 4 <= dc; e += 4) {
            int4 s4 = *(const int4*)(el + e);
            const float4* r0 = hin + s4.x * 32;
            const float4* r1 = hin + s4.y * 32;
            const float4* r2 = hin + s4.z * 32;
            const float4* r3 = hin + s4.w * 32;
            #pragma unroll
            for (int k = 0; k < 4; ++k) {
                float4 v0 = r0[q + 8 * k];
                float4 v1 = r1[q + 8 * k];
                float4 v2 = r2[q + 8 * k];
                float4 v3 = r3[q + 8 * k];
                acc[k].x += (v0.x + v1.x) + (v2.x + v3.x);
                acc[k].y += (v0.y + v1.y) + (v2.y + v3.y);
                acc[k].z += (v0.z + v1.z) + (v2.z + v3.z);
                acc[k].w += (v0.w + v1.w) + (v2.w + v3.w);
            }
        }
        for (; e < dc; ++e) {
            const float4* r0 = hin + el[e] * 32;
            #pragma unroll
            for (int k = 0; k < 4; ++k) {
                float4 va = r0[q + 8 * k];
                acc[k].x += va.x; acc[k].y += va.y;
                acc[k].z += va.z; acc[k].w += va.w;
            }
        }
        const float di = d > 0 ? 1.0f / (float)d : 0.0f;
        #pragma unroll
        for (int k = 0; k < 4; ++k) {
            acc[k].x *= di; acc[k].y *= di; acc[k].z *= di; acc[k].w *= di;
            z[nl * S4 + q + 8 * k] = acc[k];
        }
    }
    __syncthreads();

    // GEMM: out[32 x FOUT] = [agg|self][32 x 256] @ Wt + b
    constexpr int TO = FOUT / 4;       // 32 or 16
    constexpr int TN = 256 / TO;       // 8 or 16
    constexpr int NPT = 32 / TN;       // 4 or 2
    const int to = tid % TO;
    const int tn = tid / TO;

    float4 acc[NPT];
    #pragma unroll
    for (int m = 0; m < NPT; ++m) acc[m] = make_float4(0.f, 0.f, 0.f, 0.f);

    #pragma unroll 2
    for (int k4 = 0; k4 < 64; ++k4) {
        // Wt rows 4k4..4k4+3 at float4-col `to`: contiguous across lanes
        float4 w0 = Wt4[(4 * k4 + 0) * TO + to];
        float4 w1 = Wt4[(4 * k4 + 1) * TO + to];
        float4 w2 = Wt4[(4 * k4 + 2) * TO + to];
        float4 w3 = Wt4[(4 * k4 + 3) * TO + to];
        #pragma unroll
        for (int m = 0; m < NPT; ++m) {
            float4 a = z[(tn * NPT + m) * S4 + k4];   // ks 4k4..4k4+3
            acc[m].x += a.x * w0.x + a.y * w1.x + a.z * w2.x + a.w * w3.x;
            acc[m].y += a.x * w0.y + a.y * w1.y + a.z * w2.y + a.w * w3.y;
            acc[m].z += a.x * w0.z + a.y * w1.z + a.z * w2.z + a.w * w3.z;
            acc[m].w += a.x * w0.w + a.y * w1.w + a.z * w2.w + a.w * w3.w;
        }
    }

    // epilogue: +bias, optional ReLU, coalesced float4 store
    const float4 bb = ((const float4*)bias)[to];
    #pragma unroll
    for (int m = 0; m < NPT; ++m) {
        float4 o;
        o.x = acc[m].x + bb.x; o.y = acc[m].y + bb.y;
        o.z = acc[m].z + bb.z; o.w = acc[m].w + bb.w;
        if (RELU) {
            o.x = fmaxf(o.x, 0.f); o.y = fmaxf(o.y, 0.f);
            o.z = fmaxf(o.z, 0.f); o.w = fmaxf(o.w, 0.f);
        }
        ((float4*)hout)[(nodeBase + tn * NPT + m) * TO + to] = o;
    }
}

extern "C" void kernel_launch(void* const* d_in, const int* in_sizes, int n_in,
                              void* d_out, int out_size, void* d_ws, size_t ws_size,
                              hipStream_t stream) {
    const float* x = (const float*)d_in[0];
    const iv4* adj4 = (const iv4*)d_in[1];
    const float* Wl0 = (const float*)d_in[2];
    const float* b0 = (const float*)d_in[3];
    const float* Wr0 = (const float*)d_in[4];
    const float* Wl1 = (const float*)d_in[5];
    const float* b1 = (const float*)d_in[6];
    const float* Wr1 = (const float*)d_in[7];
    const float* Wl2 = (const float*)d_in[8];
    const float* b2 = (const float*)d_in[9];
    const float* Wr2 = (const float*)d_in[10];

    char* ws = (char*)d_ws;
    int* deg = (int*)(ws + OFF_DEG);
    int* slots = (int*)(ws + OFF_SLOT);
    float* wt0 = (float*)(ws + OFF_WT0);
    float* wt1 = (float*)(ws + OFF_WT1);
    float* wt2 = (float*)(ws + OFF_WT2);
    float* h1 = (float*)(ws + OFF_H1);
    float* h2 = (float*)(ws + OFF_H2);

    // 0) transpose weights + zero deg (precedes k_count on this stream)
    k_wt<<<320, 256, 0, stream>>>(Wl0, Wr0, Wl1, Wr1, Wl2, Wr2,
                                  wt0, wt1, wt2, deg);
    // 1) scan adj (the 1.07 GB roofline read), scatter edges into slots
    k_count<<<2048, 256, 0, stream>>>(adj4, deg, slots);
    // 2) three fused SAGE layers
    k_layer<128, true><<<NN / 32, 256, 0, stream>>>(
        (const float4*)x, h1, slots, deg, (const float4*)wt0, b0);
    k_layer<128, true><<<NN / 32, 256, 0, stream>>>(
        (const float4*)h1, h2, slots, deg, (const float4*)wt1, b1);
    k_layer<64, false><<<NN / 32, 256, 0, stream>>>(
        (const float4*)h2, (float*)d_out, slots, deg, (const float4*)wt2, b2);
}